// Round 7
// baseline (208.189 us; speedup 1.0000x reference)
//
#include <hip/hip_runtime.h>
#include <hip/hip_bf16.h>

// Problem constants
constexpr int B_ = 512;
constexpr int T_ = 128;
constexpr int D_ = 768;
constexpr int CD_ = 192;
constexpr int SD_ = 128;
constexpr int P_ = 128;
constexpr int FEAT_ = 321;   // CD + SD + 1
constexpr float LN_EPS_ = 1e-5f;

constexpr size_t REP_SZ   = (size_t)B_ * 2 * D_;     // 786432 floats
constexpr size_t DN16_FLT = (size_t)P_ * D_ / 2;     // 98304 u16 = 49152 floats

typedef __attribute__((ext_vector_type(8))) short short8;   // 8 bf16 (4 VGPRs)
typedef __attribute__((ext_vector_type(4))) float f32x4;

// float -> bf16 RNE
__device__ __forceinline__ unsigned short f2bf(float x) {
    unsigned u = __float_as_uint(x);
    return (unsigned short)((u + 0x7FFFu + ((u >> 16) & 1u)) >> 16);
}
__device__ __forceinline__ float bf2f(unsigned short h) {
    return __uint_as_float((unsigned)h << 16);
}

// ---------------------------------------------------------------------------
// Kernel 1: dirs_n = dirs / ||dirs||, emitted as bf16  (one block per dir)
// ---------------------------------------------------------------------------
__global__ __launch_bounds__(256) void k_dirs(const float* __restrict__ dirs,
                                              unsigned short* __restrict__ dn16) {
    int p = blockIdx.x;
    int tid = threadIdx.x;
    float s = 0.f;
    for (int d = tid; d < D_; d += 256) {
        float v = dirs[(size_t)p * D_ + d];
        s = fmaf(v, v, s);
    }
    __shared__ float red[256];
    red[tid] = s;
    __syncthreads();
    for (int off = 128; off > 0; off >>= 1) {
        if (tid < off) red[tid] += red[tid + off];
        __syncthreads();
    }
    float inv = 1.0f / sqrtf(red[0]);
    for (int d = tid; d < D_; d += 256) {
        dn16[(size_t)p * D_ + d] = f2bf(dirs[(size_t)p * D_ + d] * inv);
    }
}

// ---------------------------------------------------------------------------
// Kernel 2: col-split MFMA proj GEMM (128x64 tile per block, grid (B,2)),
// fused rep via gather-read mask-MFMA (y==0), key-rank + paired diff.
// 256 threads, LDS = 40960 B exactly -> 4 blocks/CU.
// ---------------------------------------------------------------------------
constexpr int NIT_ = 24;            // 768 / 32
constexpr int BUFU_ = 6144;         // per-buffer u16: A 4096 + B 2048

__global__ __launch_bounds__(256, 4) void k_projsort(const float* __restrict__ H,
                                                     const int* __restrict__ tt,
                                                     const int* __restrict__ attn,
                                                     const unsigned short* __restrict__ dn16,
                                                     float* __restrict__ rep,
                                                     float* __restrict__ dot2) {
    const int b = blockIdx.x;
    const int y = blockIdx.y;
    const int p0 = y * 64;
    const int tid = threadIdx.x;
    const int lane = tid & 63;
    const int w = tid >> 6;

    __shared__ __align__(16) unsigned short stage[2 * BUFU_];   // 24576 B
    __shared__ __align__(16) unsigned short proj16[8192];       // 16384 B (mask16 overlay, then permuted sortable-u16)
    // overlays in stage (dead after GEMM):
    unsigned char* xb = (unsigned char*)stage;                  // [64][64] bytes 0..4095
    unsigned char* yb = xb + 4096;                              // bytes 4096..8191
    float* dred = (float*)&stage[4096];                         // bytes 8192..9215

    // --- staging geometry; issue first tile's loads ASAP ---
    const int srow = tid >> 1;                   // 0..127 (A row)
    const int cpair = (tid & 1) * 2;             // phys chunk pair {cpair, cpair+1}
    const int swz = (srow >> 1) & 3;
    const int lo_log = (cpair ^ swz) & 2;        // logical even chunk this thread stages
    const float* gA = H + (size_t)b * T_ * D_ + (size_t)srow * D_ + lo_log * 8;
    const int brow = tid & 63;                   // B (dirs) row
    const int bphys = tid >> 6;                  // phys chunk
    const int bl = bphys ^ ((brow >> 1) & 3);    // logical chunk
    const unsigned short* gB = dn16 + (size_t)(p0 + brow) * D_ + bl * 8;
    const int aOff = srow * 32;                  // u16 offset of A row
    const int physA0 = lo_log ^ swz;             // phys chunk of logical lo_log

    float4 fa0 = *reinterpret_cast<const float4*>(gA);
    float4 fa1 = *reinterpret_cast<const float4*>(gA + 4);
    float4 fa2 = *reinterpret_cast<const float4*>(gA + 8);
    float4 fa3 = *reinterpret_cast<const float4*>(gA + 12);
    short8 bv = *reinterpret_cast<const short8*>(gB);

    // --- phase 0: masks via ballot, counts, my row's pos, bf16 mask rows ---
    const int wr = w & 1;             // row half this wave owns (rows 64*wr..)
    const int wc2 = w >> 1;           // col half within the 64-col tile
    const int myt = 64 * wr + lane;
    int v_tt = tt[b * T_ + myt];
    int v_at = attn[b * T_ + myt];
    bool m0 = (v_tt == 0) && (v_at == 1);
    bool m1 = (v_tt == 1) && (v_at == 1);
    unsigned long long bal0 = __ballot(m0);
    unsigned long long bal1 = __ballot(m1);
    if (w < 2 && lane == 0) {
        ((unsigned long long*)stage)[w * 2] = bal0;
        ((unsigned long long*)stage)[w * 2 + 1] = bal1;
    }
    if (tid < 128) {    // bf16 mask rows (1.0/0.0) into proj16[0..255] overlay
        proj16[tid] = m0 ? 0x3F80u : 0u;
        proj16[128 + tid] = m1 ? 0x3F80u : 0u;
    }
    __syncthreads();
    const unsigned long long lo0 = ((unsigned long long*)stage)[0];
    const unsigned long long lo1 = ((unsigned long long*)stage)[1];
    const unsigned long long hi0 = ((unsigned long long*)stage)[2];
    const unsigned long long hi1 = ((unsigned long long*)stage)[3];
    const int n0 = __popcll(lo0) + __popcll(hi0);
    const int n1 = __popcll(lo1) + __popcll(hi1);
    const int ntot = n0 + n1;
    const float inv0 = 1.f / (float)max(n0, 1);
    const float inv1 = 1.f / (float)max(n1, 1);
    unsigned long long below = (lane == 63) ? 0xFFFFFFFFFFFFFFFFull >> 1
                                            : ((1ull << lane) - 1ull);
    below = (1ull << lane) - 1ull;   // lane<64 -> safe (1ull<<63 ok)
    int mypos = 0xFF;
    if (m0) mypos = (wr ? __popcll(lo0) : 0) + __popcll((wr ? hi0 : lo0) & below);
    else if (m1) mypos = n0 + (wr ? __popcll(lo1) : 0) + __popcll((wr ? hi1 : lo1) & below);
    __syncthreads();   // ballot scratch consumed before staging overwrites

    // --- phase 1: GEMM + fused rep ---
    const int fr = lane & 15;
    const int kg = lane >> 4;
    int addrA[4], addrB[2];
#pragma unroll
    for (int m = 0; m < 4; ++m) {
        int row = 64 * wr + 16 * m + fr;
        addrA[m] = row * 32 + (kg ^ ((row >> 1) & 3)) * 8;
    }
#pragma unroll
    for (int n = 0; n < 2; ++n) {
        int row = 32 * wc2 + 16 * n + fr;
        addrB[n] = 4096 + row * 32 + (kg ^ ((row >> 1) & 3)) * 8;
    }
    const bool repy = (y == 0);
    const int grp = w & 1;
    const int dl = grp * 16 + fr;     // rep d_local 0..31
    const int dch = dl >> 3, dsub = dl & 7;
    float* repb = rep + (size_t)b * 2 * D_;

    f32x4 acc[4][2];
#pragma unroll
    for (int m = 0; m < 4; ++m)
#pragma unroll
        for (int n = 0; n < 2; ++n) acc[m][n] = (f32x4){0.f, 0.f, 0.f, 0.f};

    for (int it = 0; it < NIT_; ++it) {
        const int base = (it & 1) * BUFU_;
        // convert + stage (linear writes; source pre-swizzled)
        short8 w0, w1;
        w0[0] = (short)f2bf(fa0.x); w0[1] = (short)f2bf(fa0.y);
        w0[2] = (short)f2bf(fa0.z); w0[3] = (short)f2bf(fa0.w);
        w0[4] = (short)f2bf(fa1.x); w0[5] = (short)f2bf(fa1.y);
        w0[6] = (short)f2bf(fa1.z); w0[7] = (short)f2bf(fa1.w);
        w1[0] = (short)f2bf(fa2.x); w1[1] = (short)f2bf(fa2.y);
        w1[2] = (short)f2bf(fa2.z); w1[3] = (short)f2bf(fa2.w);
        w1[4] = (short)f2bf(fa3.x); w1[5] = (short)f2bf(fa3.y);
        w1[6] = (short)f2bf(fa3.z); w1[7] = (short)f2bf(fa3.w);
        *reinterpret_cast<short8*>(&stage[base + aOff + physA0 * 8]) = w0;
        *reinterpret_cast<short8*>(&stage[base + aOff + (physA0 ^ 1) * 8]) = w1;
        *reinterpret_cast<short8*>(&stage[base + 4096 + brow * 32 + bphys * 8]) = bv;
        if (repy && srow == 0) {   // cls = H[b,0,:] exact fp32
            float* cd = repb + it * 32 + lo_log * 8;
            *reinterpret_cast<float4*>(cd)     = fa0;
            *reinterpret_cast<float4*>(cd + 4) = fa1;
            *reinterpret_cast<float4*>(cd + 8) = fa2;
            *reinterpret_cast<float4*>(cd + 12) = fa3;
        }
        // issue next tile's loads (in flight across MFMA + barriers)
        if (it + 1 < NIT_) {
            int k = (it + 1) * 32;
            fa0 = *reinterpret_cast<const float4*>(gA + k);
            fa1 = *reinterpret_cast<const float4*>(gA + k + 4);
            fa2 = *reinterpret_cast<const float4*>(gA + k + 8);
            fa3 = *reinterpret_cast<const float4*>(gA + k + 12);
            bv = *reinterpret_cast<const short8*>(gB + k);
        }
        asm volatile("s_waitcnt lgkmcnt(0)" ::: "memory");
        __builtin_amdgcn_s_barrier();
        asm volatile("" ::: "memory");

        short8 af[4], bf_[2];
#pragma unroll
        for (int m = 0; m < 4; ++m)
            af[m] = *reinterpret_cast<const short8*>(&stage[base + addrA[m]]);
#pragma unroll
        for (int n = 0; n < 2; ++n)
            bf_[n] = *reinterpret_cast<const short8*>(&stage[base + addrB[n]]);
#pragma unroll
        for (int m = 0; m < 4; ++m)
#pragma unroll
            for (int n = 0; n < 2; ++n)
                acc[m][n] = __builtin_amdgcn_mfma_f32_16x16x32_bf16(af[m], bf_[n], acc[m][n], 0, 0, 0);

        // fused rep: duty rotates over wave pairs by iter parity (y==0 only)
        if (repy && (((it & 1) == 0) == (w < 2))) {
            f32x4 ar = (f32x4){0.f, 0.f, 0.f, 0.f};
#pragma unroll
            for (int tc = 0; tc < 4; ++tc) {
                int tbase = tc * 32 + kg * 8;
                short8 am = {0, 0, 0, 0, 0, 0, 0, 0};
                if (fr < 2) am = *reinterpret_cast<const short8*>(&proj16[fr * 128 + tbase]);
                short8 bm;
#pragma unroll
                for (int j = 0; j < 8; ++j) {
                    int t = tbase + j;
                    bm[j] = (short)stage[base + t * 32 + (dch ^ ((t >> 1) & 3)) * 8 + dsub];
                }
                ar = __builtin_amdgcn_mfma_f32_16x16x32_bf16(am, bm, ar, 0, 0, 0);
            }
            if (lane < 16)
                repb[D_ + it * 32 + grp * 16 + lane] = ar[0] * inv0 - ar[1] * inv1;
        }
        asm volatile("" ::: "memory");
        __builtin_amdgcn_s_barrier();
        asm volatile("" ::: "memory");
    }

    // epilogue: write proj16 group-permuted (pos via shfl) as sortable u16
#pragma unroll
    for (int m = 0; m < 4; ++m) {
#pragma unroll
        for (int r = 0; r < 4; ++r) {
            int rowlane = 16 * m + kg * 4 + r;       // row within wave's 64-half
            int pp = __shfl(mypos, rowlane);
            if (pp != 0xFF) {
#pragma unroll
                for (int n = 0; n < 2; ++n) {
                    int col = 32 * wc2 + 16 * n + fr;
                    unsigned bb = f2bf(acc[m][n][r]);
                    unsigned su = bb ^ ((bb >> 15) ? 0xFFFFu : 0x8000u);
                    proj16[pp * 64 + col] = (unsigned short)su;
                }
            }
        }
    }
    __syncthreads();

    // --- phase 2: ranking via sortable-u32 keys, 2 passes x 16 keys ---
    const int mmv = min(n0, n1);      // <= 64
    const int c = tid & 63;
    const int q = tid >> 6;           // 0..3
#pragma unroll
    for (int pass = 0; pass < 2; ++pass) {
        const int pbase = q * 32 + pass * 16;
        unsigned kv[16];
        int cnt[16];
#pragma unroll
        for (int ii = 0; ii < 16; ++ii) {
            int p = pbase + ii;
            unsigned key = 0xFFFFFFFFu;
            if (p < ntot) {
                unsigned su = proj16[p * 64 + c];
                key = ((unsigned)(p >= n0) << 31) | (su << 8) | (unsigned)p;
            }
            kv[ii] = key;
            cnt[ii] = 0;
        }
        int lo, hi;
        if (pbase + 16 <= n0) { lo = 0;  hi = n0;   }
        else if (pbase >= n0) { lo = n0; hi = ntot; }
        else                  { lo = 0;  hi = ntot; }
        for (int j = lo; j < hi; ++j) {
            unsigned su = proj16[j * 64 + c];
            unsigned kw = ((unsigned)(j >= n0) << 31) | (su << 8) | (unsigned)j;
#pragma unroll
            for (int ii = 0; ii < 16; ++ii) cnt[ii] += (kw < kv[ii]) ? 1 : 0;
        }
#pragma unroll
        for (int ii = 0; ii < 16; ++ii) {
            int p = pbase + ii;
            if (p < ntot) {
                int rank = cnt[ii] - ((p >= n0 && lo == 0) ? n0 : 0);
                if (rank < mmv) {
                    unsigned char* buf = (p >= n0) ? yb : xb;
                    buf[rank * 64 + c] = (unsigned char)p;
                }
            }
        }
    }
    __syncthreads();

    // --- phase 3: paired diff per column, max over columns ---
    float part = 0.f;
    for (int r = q; r < mmv; r += 4) {
        unsigned sx = proj16[(int)xb[r * 64 + c] * 64 + c];
        unsigned sy = proj16[(int)yb[r * 64 + c] * 64 + c];
        unsigned bx = sx ^ ((sx >> 15) ? 0x8000u : 0xFFFFu);
        unsigned byv = sy ^ ((sy >> 15) ? 0x8000u : 0xFFFFu);
        part += fabsf(bf2f((unsigned short)bx) - bf2f((unsigned short)byv));
    }
    dred[tid] = part;
    __syncthreads();
    if (tid < 64) {
        float invm = 1.f / (float)max(mmv, 1);
        float s = (dred[tid] + dred[tid + 64] + dred[tid + 128] + dred[tid + 192]) * invm;
        float m = s;
#pragma unroll
        for (int off = 32; off > 0; off >>= 1) m = fmaxf(m, __shfl_xor(m, off));
        if (tid == 0) dot2[b * 2 + y] = m;
    }
}

// ---------------------------------------------------------------------------
// Kernel 3: head — C/S GEMV + gate + LayerNorm + logits.
// 320 threads (1 output each), 4 batches per block, wave-parallel LN.
// ---------------------------------------------------------------------------
__global__ __launch_bounds__(320) void k_head(const float* __restrict__ rep,
                                              const float* __restrict__ Wc,
                                              const float* __restrict__ bc,
                                              const float* __restrict__ Ws,
                                              const float* __restrict__ bs,
                                              const float* __restrict__ gate,
                                              const float* __restrict__ lng,
                                              const float* __restrict__ lnb,
                                              const float* __restrict__ Wcls,
                                              const float* __restrict__ bcls,
                                              const float* __restrict__ dot2,
                                              float* __restrict__ out) {
    int b0 = blockIdx.x * 4;
    int tid = threadIdx.x;
    __shared__ __align__(16) float repS[4 * 1536];   // 24 KB
    __shared__ float featS[4 * FEAT_];

    const float4* repg = reinterpret_cast<const float4*>(rep + (size_t)b0 * 1536);
    float4* repl = reinterpret_cast<float4*>(repS);
    for (int i = tid; i < 1536; i += 320) repl[i] = repg[i];
    __syncthreads();

    float g = 1.f / (1.f + expf(-gate[0]));

    {   // each thread: one output o over 4 batches
        int o = tid;  // 0..319
        bool isC = o < CD_;
        const float* w = isC ? (Wc + (size_t)o * 1536) : (Ws + (size_t)(o - CD_) * 1536);
        float bias = isC ? bc[o] : bs[o - CD_];
        float scale = isC ? (1.f - g) : g;
        const float4* w4 = reinterpret_cast<const float4*>(w);
        float a0 = 0.f, a1 = 0.f, a2 = 0.f, a3 = 0.f;
        for (int k4 = 0; k4 < 384; ++k4) {
            float4 wv = w4[k4];
            float4 r0 = repl[k4];
            float4 r1 = repl[384 + k4];
            float4 r2 = repl[768 + k4];
            float4 r3 = repl[1152 + k4];
            a0 += fmaf(wv.x, r0.x, fmaf(wv.y, r0.y, fmaf(wv.z, r0.z, wv.w * r0.w)));
            a1 += fmaf(wv.x, r1.x, fmaf(wv.y, r1.y, fmaf(wv.z, r1.z, wv.w * r1.w)));
            a2 += fmaf(wv.x, r2.x, fmaf(wv.y, r2.y, fmaf(wv.z, r2.z, wv.w * r2.w)));
            a3 += fmaf(wv.x, r3.x, fmaf(wv.y, r3.y, fmaf(wv.z, r3.z, wv.w * r3.w)));
        }
        featS[0 * FEAT_ + o] = (a0 + bias) * scale;
        featS[1 * FEAT_ + o] = (a1 + bias) * scale;
        featS[2 * FEAT_ + o] = (a2 + bias) * scale;
        featS[3 * FEAT_ + o] = (a3 + bias) * scale;
    }
    if (tid < 4) {
        int bb = b0 + tid;
        featS[tid * FEAT_ + 320] = fmaxf(dot2[bb * 2], dot2[bb * 2 + 1]);
    }
    __syncthreads();

    int w = tid >> 6, lane = tid & 63;
    if (w < 4) {   // wave w handles batch b0+w
        const float* f = featS + w * FEAT_;
        float s = 0.f, s2 = 0.f;
        for (int i = lane; i < FEAT_; i += 64) {
            float v = f[i];
            s += v;
            s2 = fmaf(v, v, s2);
        }
#pragma unroll
        for (int off = 32; off > 0; off >>= 1) {
            s += __shfl_xor(s, off);
            s2 += __shfl_xor(s2, off);
        }
        float mu = s * (1.f / (float)FEAT_);
        float var = fmaxf(s2 * (1.f / (float)FEAT_) - mu * mu, 0.f);
        float rstd = 1.0f / sqrtf(var + LN_EPS_);
        float l0 = 0.f, l1 = 0.f;
        for (int i = lane; i < FEAT_; i += 64) {
            float nv = (f[i] - mu) * rstd * lng[i] + lnb[i];
            l0 = fmaf(nv, Wcls[i], l0);
            l1 = fmaf(nv, Wcls[FEAT_ + i], l1);
        }
#pragma unroll
        for (int off = 32; off > 0; off >>= 1) {
            l0 += __shfl_xor(l0, off);
            l1 += __shfl_xor(l1, off);
        }
        if (lane == 0) {
            out[(size_t)(b0 + w) * 2 + 0] = l0 + bcls[0];
            out[(size_t)(b0 + w) * 2 + 1] = l1 + bcls[1];
        }
    }
}

// ---------------------------------------------------------------------------
// Kernel 4/5: ortho = mean((Wc @ Ws^T)^2), deterministic two-stage reduction
// ---------------------------------------------------------------------------
__global__ __launch_bounds__(256) void k_ortho(const float* __restrict__ Wc,
                                               const float* __restrict__ Ws,
                                               float* __restrict__ part) {
    int i = blockIdx.x;    // Wc row, 0..191
    int tid = threadIdx.x;
    __shared__ float wrow[1536];
    __shared__ float tmp[256];
    for (int k = tid; k < 1536; k += 256) wrow[k] = Wc[(size_t)i * 1536 + k];
    __syncthreads();
    int j = tid & 127, h = tid >> 7;    // split each dot across 2 threads
    const float* wsr = Ws + (size_t)j * 1536 + h * 768;
    const float* wr = wrow + h * 768;
    float s = 0.f;
    for (int k = 0; k < 768; ++k) s = fmaf(wr[k], wsr[k], s);
    tmp[tid] = s;
    __syncthreads();
    if (tid < 128) {
        float d = tmp[tid] + tmp[tid + 128];
        tmp[tid] = d * d;
    }
    __syncthreads();
    for (int off = 64; off > 0; off >>= 1) {
        if (tid < off) tmp[tid] += tmp[tid + off];
        __syncthreads();
    }
    if (tid == 0) part[i] = tmp[0];
}

__global__ __launch_bounds__(256) void k_ortho2(const float* __restrict__ part,
                                                float* __restrict__ out) {
    int tid = threadIdx.x;
    __shared__ float red[256];
    red[tid] = (tid < CD_) ? part[tid] : 0.f;
    __syncthreads();
    for (int off = 128; off > 0; off >>= 1) {
        if (tid < off) red[tid] += red[tid + off];
        __syncthreads();
    }
    if (tid == 0) out[(size_t)B_ * 2] = red[0] / (float)(CD_ * SD_);
}

// ---------------------------------------------------------------------------
extern "C" void kernel_launch(void* const* d_in, const int* in_sizes, int n_in,
                              void* d_out, int out_size, void* d_ws, size_t ws_size,
                              hipStream_t stream) {
    const float* H    = (const float*)d_in[0];
    const int*   tt   = (const int*)d_in[1];
    const int*   attn = (const int*)d_in[2];
    const float* Wc   = (const float*)d_in[3];
    const float* bc   = (const float*)d_in[4];
    const float* Ws   = (const float*)d_in[5];
    const float* bs   = (const float*)d_in[6];
    const float* gate = (const float*)d_in[7];
    const float* lng  = (const float*)d_in[8];
    const float* lnb  = (const float*)d_in[9];
    const float* Wcls = (const float*)d_in[10];
    const float* bcls = (const float*)d_in[11];
    const float* dirs = (const float*)d_in[12];

    float* ws    = (float*)d_ws;
    float* rep   = ws;                                      // [B][1536] fp32
    unsigned short* dn16 = (unsigned short*)(ws + REP_SZ);  // [P][D] bf16
    float* dot2  = ws + REP_SZ + DN16_FLT;                  // [B][2]
    float* part  = dot2 + 2 * B_;                           // [CD]
    float* out   = (float*)d_out;

    k_dirs<<<P_, 256, 0, stream>>>(dirs, dn16);
    k_projsort<<<dim3(B_, 2), 256, 0, stream>>>(H, tt, attn, dn16, rep, dot2);
    k_head<<<B_ / 4, 320, 0, stream>>>(rep, Wc, bc, Ws, bs, gate, lng, lnb, Wcls, bcls, dot2, out);
    k_ortho<<<CD_, 256, 0, stream>>>(Wc, Ws, part);
    k_ortho2<<<1, 256, 0, stream>>>(part, out);
}